// Round 6
// baseline (328.206 us; speedup 1.0000x reference)
//
#include <hip/hip_runtime.h>

// RobustSum: M = A@V; 3x { dist=cdist(M,V); w=1/(dist+eps); ww=w*A;
//                          M = (ww/rowsum(ww)) @ V }   (T=1.0)
// bf16 MFMA; tolerance = 2% of ref absmax (margin 5.3x at bf16).
//
// Round 14 (319.4us base = r13 structure + T1). Eliminate all 4 reduce
// dispatches + the part round-trip: W@V GEMM re-tiled to 128x64, grid
// (8,16,4)=512 blocks (2/CU), FULL K=2048 -> no split-K partials. Epilogue
// does the l1 scaling (sums 16 l1p slots), writes Mbf (or fp32 out) direct,
// and accumulates m2 row-norms via fp32 atomicAdd (8 adds/addr). m2 double-
// buffered: cast zeroes m2a; each MODE-1 dispatch zeroes the buffer the NEXT
// W@V writes (read/write always on distinct buffers, stream-ordered).
// 13 -> 9 dispatches. Numerics: full-K fp32 accum (better than bf16 parts).

typedef __bf16 bf16;
typedef bf16 bf16x4 __attribute__((ext_vector_type(4)));
typedef bf16 bf16x8 __attribute__((ext_vector_type(8)));
typedef float f32x4 __attribute__((ext_vector_type(4)));

#define S_DIM 2048
#define D_DIM 512
#define NB    4
#define EPSILON 0.01f

#define AS1 __attribute__((address_space(1)))
#define AS3 __attribute__((address_space(3)))

// ---------------- cast fp32 -> bf16 (x4) + zero m2a ----------------
__global__ void cast_kernel(const float* __restrict__ in, bf16* __restrict__ out,
                            int n4, float* __restrict__ m2z) {
  if (blockIdx.x < 32) m2z[blockIdx.x * 256 + threadIdx.x] = 0.f;  // NB*S floats
  int i = blockIdx.x * blockDim.x + threadIdx.x;
  if (i >= n4) return;
  float4 v = ((const float4*)in)[i];
  bf16x4 o = { (bf16)v.x, (bf16)v.y, (bf16)v.z, (bf16)v.w };
  ((bf16x4*)out)[i] = o;
}

// -- V preproc: V fp32 -> Vbf + Vt (bf16) + v2 row L2^2 (non-atomic) --
__global__ void vprep_kernel(const float* __restrict__ V, bf16* __restrict__ Vbf,
                             bf16* __restrict__ Vt, float* __restrict__ v2) {
  __shared__ float tile[64][68];
  int b  = blockIdx.y;
  int r0 = blockIdx.x * 64;
  const float* Vb = V   + (size_t)b * S_DIM * D_DIM;
  bf16*       Vfb = Vbf + (size_t)b * S_DIM * D_DIM;
  bf16*       Vtb = Vt  + (size_t)b * S_DIM * D_DIM;
  float*      v2b = v2  + (size_t)b * S_DIM;
  int tx = threadIdx.x & 15, ty = threadIdx.x >> 4;   // ty 0..15
  float acc2[4] = { 0.f, 0.f, 0.f, 0.f };
  for (int c = 0; c < 8; ++c) {
    int c0 = c * 64;
#pragma unroll
    for (int i = 0; i < 4; ++i) {
      int r = ty + i * 16;
      float4 v = *(const float4*)(Vb + (size_t)(r0 + r) * D_DIM + (c0 + tx * 4));
      tile[r][tx * 4 + 0] = v.x; tile[r][tx * 4 + 1] = v.y;
      tile[r][tx * 4 + 2] = v.z; tile[r][tx * 4 + 3] = v.w;
      bf16x4 o = { (bf16)v.x, (bf16)v.y, (bf16)v.z, (bf16)v.w };
      *(bf16x4*)(Vfb + (size_t)(r0 + r) * D_DIM + (c0 + tx * 4)) = o;
#pragma unroll
      for (int j = 0; j < 4; ++j) { float f = (float)o[j]; acc2[i] += f * f; }
    }
    __syncthreads();
#pragma unroll
    for (int i = 0; i < 4; ++i) {
      int cc = ty + i * 16;
      bf16x4 o = { (bf16)tile[tx * 4 + 0][cc], (bf16)tile[tx * 4 + 1][cc],
                   (bf16)tile[tx * 4 + 2][cc], (bf16)tile[tx * 4 + 3][cc] };
      *(bf16x4*)(Vtb + (size_t)(c0 + cc) * S_DIM + (r0 + tx * 4)) = o;
    }
    __syncthreads();   // tile reused next chunk
  }
#pragma unroll
  for (int i = 0; i < 4; ++i) {
    float s = acc2[i];
    s += __shfl_xor(s, 1); s += __shfl_xor(s, 2);
    s += __shfl_xor(s, 4); s += __shfl_xor(s, 8);
    if (tx == 0) v2b[r0 + ty + i * 16] = s;
  }
}

// ---------------- P-GEMM (MODE-1): P = M@V^T + dist/weight epilogue ----------------
// grid (16,16,NB), 256 thr. Writes Wbf + 16-slot l1p. Also zeroes m2z (the
// buffer the following W@V dispatch atomically accumulates into).
__global__ __launch_bounds__(256, 4)
void gemmP_kernel(const bf16* __restrict__ Amat, const bf16* __restrict__ Bmat,
                  int M, int N, int K,
                  const float* __restrict__ m2, const float* __restrict__ v2,
                  const bf16* __restrict__ Aw, bf16* __restrict__ Wout,
                  float* __restrict__ l1p, float* __restrict__ m2z) {
  const int bz = blockIdx.z;
  // T1 XCD-chunked bijective swizzle (nwg = 256, %8==0)
  const int gx  = gridDim.x;
  const int nwg = gx * gridDim.y;
  int lin = blockIdx.y * gx + blockIdx.x;
  lin = (lin & 7) * (nwg >> 3) + (lin >> 3);
  const int bx = lin % gx;
  const int by = lin / gx;

  // zero the NEXT m2 buffer (disjoint from m2 read below; stream-ordered
  // before the W@V dispatch that accumulates it)
  if (bx == 0 && threadIdx.x < 128)
    m2z[(size_t)bz * S_DIM + by * 128 + threadIdx.x] = 0.f;

  const int row0 = by * 128;
  const int col0 = bx * 128;
  const bf16* Ab = Amat + (size_t)bz * M * K;
  const bf16* Bb = Bmat + (size_t)bz * N * K;

  __shared__ char smem[33792];
  bf16*  ldsA = (bf16*)smem;
  bf16*  ldsB = (bf16*)(smem + 16384);
  float* ldsW = (float*)smem;

  const int tid  = threadIdx.x;
  const int wave = tid >> 6;
  const int lane = tid & 63;
  const int wr   = wave >> 1;
  const int wc   = wave & 1;
  const int q    = lane >> 4;
  const int c16  = lane & 15;
  const int srow = lane >> 3;
  const int scol = ((lane & 7) ^ srow) * 8;

  f32x4 acc[4][4] = {};

  for (int k0 = 0; k0 < K; k0 += 64) {
#pragma unroll
    for (int i = 0; i < 4; ++i) {
      int slot = wave * 4 + i;
      int r = slot * 8 + srow;
      __builtin_amdgcn_global_load_lds(
          (const AS1 void*)(Ab + (size_t)(row0 + r) * K + (k0 + scol)),
          (AS3 void*)(ldsA + slot * 512), 16, 0, 0);
      __builtin_amdgcn_global_load_lds(
          (const AS1 void*)(Bb + (size_t)(col0 + r) * K + (k0 + scol)),
          (AS3 void*)(ldsB + slot * 512), 16, 0, 0);
    }
    __syncthreads();

#pragma unroll
    for (int kk = 0; kk < 2; ++kk) {
      bf16x8 afr[4], bfr[4];
#pragma unroll
      for (int mt = 0; mt < 4; ++mt) {
        int R = wr * 64 + mt * 16 + c16;
        int p = ((kk << 2) + q) ^ (c16 & 7);
        afr[mt] = *(const bf16x8*)(ldsA + (size_t)R * 64 + p * 8);
      }
#pragma unroll
      for (int nt = 0; nt < 4; ++nt) {
        int R = wc * 64 + nt * 16 + c16;
        int p = ((kk << 2) + q) ^ (c16 & 7);
        bfr[nt] = *(const bf16x8*)(ldsB + (size_t)R * 64 + p * 8);
      }
#pragma unroll
      for (int mt = 0; mt < 4; ++mt)
#pragma unroll
        for (int nt = 0; nt < 4; ++nt)
          acc[mt][nt] = __builtin_amdgcn_mfma_f32_16x16x32_bf16(afr[mt], bfr[nt], acc[mt][nt], 0, 0, 0);
    }
    __syncthreads();
  }

  const int rowBase = row0 + wr * 64 + q * 4;
  const int colBase = col0 + wc * 64 + c16;

  // w = rcp(sqrt(max(m2+v2-2P,0)) + eps), in place
  {
    const float* m2b = m2 + (size_t)bz * M;
    const float* v2b = v2 + (size_t)bz * N;
    float v2v[4];
#pragma unroll
    for (int nt = 0; nt < 4; ++nt) v2v[nt] = v2b[colBase + nt * 16];
#pragma unroll
    for (int mt = 0; mt < 4; ++mt)
#pragma unroll
      for (int r = 0; r < 4; ++r) {
        float m2v = m2b[rowBase + mt * 16 + r];
#pragma unroll
        for (int nt = 0; nt < 4; ++nt) {
          float d2 = fmaxf(m2v + v2v[nt] - 2.f * acc[mt][nt][r], 0.f);
          acc[mt][nt][r] = __builtin_amdgcn_rcpf(__builtin_amdgcn_sqrtf(d2) + EPSILON);
        }
      }
  }

  // LDS transpose in 2 halves of 64 rows -> vectorized global I/O
  const int lr  = tid >> 3;   // 0..31
  const int sub = tid & 7;    // 0..7
#pragma unroll
  for (int h = 0; h < 2; ++h) {
    __syncthreads();
    if (wr == h) {
#pragma unroll
      for (int mt = 0; mt < 4; ++mt)
#pragma unroll
        for (int nt = 0; nt < 4; ++nt)
#pragma unroll
          for (int r = 0; r < 4; ++r)
            ldsW[(mt * 16 + q * 4 + r) * 132 + wc * 64 + nt * 16 + c16] = acc[mt][nt][r];
    }
    __syncthreads();
#pragma unroll
    for (int h2 = 0; h2 < 2; ++h2) {
      int rloc = lr + 32 * h2;            // 0..63
      int gi = row0 + 64 * h + rloc;
      const float* wp = ldsW + rloc * 132 + sub * 16;
      float4 w0 = *(const float4*)(wp + 0);
      float4 w1 = *(const float4*)(wp + 4);
      float4 w2 = *(const float4*)(wp + 8);
      float4 w3 = *(const float4*)(wp + 12);
      float wv_[16] = { w0.x, w0.y, w0.z, w0.w, w1.x, w1.y, w1.z, w1.w,
                        w2.x, w2.y, w2.z, w2.w, w3.x, w3.y, w3.z, w3.w };
      const bf16* ap = Aw + (size_t)bz * M * N + (size_t)gi * N + (col0 + sub * 16);
      bf16x8 a0 = *(const bf16x8*)(ap);
      bf16x8 a1 = *(const bf16x8*)(ap + 8);
      bf16x8 o0, o1;
      float rs = 0.f;
#pragma unroll
      for (int e = 0; e < 8; ++e) {
        float x0 = wv_[e] * (float)a0[e];
        float x1 = wv_[e + 8] * (float)a1[e];
        o0[e] = (bf16)x0; o1[e] = (bf16)x1;
        rs += fabsf(x0) + fabsf(x1);
      }
      bf16* op = Wout + (size_t)bz * M * N + (size_t)gi * N + (col0 + sub * 16);
      *(bf16x8*)(op)     = o0;
      *(bf16x8*)(op + 8) = o1;
      rs += __shfl_xor(rs, 1);
      rs += __shfl_xor(rs, 2);
      rs += __shfl_xor(rs, 4);
      if (sub == 0) l1p[((size_t)bx * NB + bz) * M + gi] = rs;
    }
  }
}

// ---------------- W@V GEMM, 128x64 tile, FULL K=2048, no split-K ----------------
// SCALED 0: Mo + m2 atomics (M0 = A@V) ; 1: l1-scale -> Mo + m2 atomics ;
// SCALED 2: l1-scale -> fp32 out (final iteration).
// grid (8,16,NB), 256 thr, 2 blocks/CU.
template <int SCALED>
__global__ __launch_bounds__(256, 4)
void gemmwv_kernel(const bf16* __restrict__ Amat, const bf16* __restrict__ Bmat,
                   const float* __restrict__ l1p, bf16* __restrict__ Mo,
                   float* __restrict__ Fo, float* __restrict__ m2out) {
  const int bz = blockIdx.z;
  // T1 XCD-chunked bijective swizzle (nwg = 128, %8==0)
  const int gx  = gridDim.x;
  const int nwg = gx * gridDim.y;
  int lin = blockIdx.y * gx + blockIdx.x;
  lin = (lin & 7) * (nwg >> 3) + (lin >> 3);
  const int bx = lin % gx;
  const int by = lin / gx;

  const int row0 = by * 128;
  const int col0 = bx * 64;
  const bf16* Ab = Amat + (size_t)bz * S_DIM * S_DIM;   // W (or Abf), [S][S]
  const bf16* Bb = Bmat + (size_t)bz * S_DIM * D_DIM;   // Vt, [D][S]

  __shared__ char smem[24576];
  bf16*  ldsA = (bf16*)smem;                 // 128 x 64 bf16 = 16 KB
  bf16*  ldsB = (bf16*)(smem + 16384);       // 64 x 64 bf16 = 8 KB
  float* ldsW = (float*)smem;                // 64 x 68 f32 epilogue slab

  const int tid  = threadIdx.x;
  const int wave = tid >> 6;
  const int lane = tid & 63;
  const int wr   = wave >> 1;   // 0..1 -> 64-row half
  const int wc   = wave & 1;    // 0..1 -> 32-col half
  const int q    = lane >> 4;
  const int c16  = lane & 15;
  const int srow = lane >> 3;
  const int scol = ((lane & 7) ^ srow) * 8;

  f32x4 acc[4][2] = {};

  for (int k0 = 0; k0 < S_DIM; k0 += 64) {
#pragma unroll
    for (int i = 0; i < 4; ++i) {
      int slot = wave * 4 + i;                // 0..15
      int r = slot * 8 + srow;
      __builtin_amdgcn_global_load_lds(
          (const AS1 void*)(Ab + (size_t)(row0 + r) * S_DIM + (k0 + scol)),
          (AS3 void*)(ldsA + slot * 512), 16, 0, 0);
    }
#pragma unroll
    for (int i = 0; i < 2; ++i) {
      int slot = wave * 2 + i;                // 0..7
      int r = slot * 8 + srow;
      __builtin_amdgcn_global_load_lds(
          (const AS1 void*)(Bb + (size_t)(col0 + r) * S_DIM + (k0 + scol)),
          (AS3 void*)(ldsB + slot * 512), 16, 0, 0);
    }
    __syncthreads();

#pragma unroll
    for (int kk = 0; kk < 2; ++kk) {
      bf16x8 afr[4], bfr[2];
      const int p = ((kk << 2) + q) ^ (c16 & 7);
#pragma unroll
      for (int mt = 0; mt < 4; ++mt)
        afr[mt] = *(const bf16x8*)(ldsA + (size_t)(wr * 64 + mt * 16 + c16) * 64 + p * 8);
#pragma unroll
      for (int nt = 0; nt < 2; ++nt)
        bfr[nt] = *(const bf16x8*)(ldsB + (size_t)(wc * 32 + nt * 16 + c16) * 64 + p * 8);
#pragma unroll
      for (int mt = 0; mt < 4; ++mt)
#pragma unroll
        for (int nt = 0; nt < 2; ++nt)
          acc[mt][nt] = __builtin_amdgcn_mfma_f32_16x16x32_bf16(afr[mt], bfr[nt], acc[mt][nt], 0, 0, 0);
    }
    __syncthreads();
  }

  // epilogue: slab-transpose 2 halves of 64 rows; per-row l1 scale; m2 atomics
  const int lr  = tid >> 2;    // 0..63
  const int sub = tid & 3;     // 0..3 (16-col chunk)
#pragma unroll
  for (int h = 0; h < 2; ++h) {
    __syncthreads();
    if (wr == h) {
#pragma unroll
      for (int mt = 0; mt < 4; ++mt)
#pragma unroll
        for (int nt = 0; nt < 2; ++nt)
#pragma unroll
          for (int r = 0; r < 4; ++r)
            ldsW[(mt * 16 + q * 4 + r) * 68 + wc * 32 + nt * 16 + c16] = acc[mt][nt][r];
    }
    __syncthreads();
    const int gi = row0 + 64 * h + lr;
    const float* wp = ldsW + lr * 68 + sub * 16;
    float4 w0 = *(const float4*)(wp + 0);
    float4 w1 = *(const float4*)(wp + 4);
    float4 w2 = *(const float4*)(wp + 8);
    float4 w3 = *(const float4*)(wp + 12);
    float wv_[16] = { w0.x, w0.y, w0.z, w0.w, w1.x, w1.y, w1.z, w1.w,
                      w2.x, w2.y, w2.z, w2.w, w3.x, w3.y, w3.z, w3.w };
    float sc = 1.f;
    if (SCALED >= 1) {
      float l1v = 0.f;
#pragma unroll
      for (int e = 0; e < 16; ++e) l1v += l1p[((size_t)e * NB + bz) * S_DIM + gi];
      sc = __builtin_amdgcn_rcpf(fmaxf(l1v, 1e-12f));
    }
#pragma unroll
    for (int e = 0; e < 16; ++e) wv_[e] *= sc;
    if (SCALED == 2) {
      float* op = Fo + (size_t)bz * S_DIM * D_DIM + (size_t)gi * D_DIM + col0 + sub * 16;
      float4 o0 = { wv_[0], wv_[1], wv_[2], wv_[3] };
      float4 o1 = { wv_[4], wv_[5], wv_[6], wv_[7] };
      float4 o2 = { wv_[8], wv_[9], wv_[10], wv_[11] };
      float4 o3 = { wv_[12], wv_[13], wv_[14], wv_[15] };
      *(float4*)(op + 0)  = o0; *(float4*)(op + 4)  = o1;
      *(float4*)(op + 8)  = o2; *(float4*)(op + 12) = o3;
    } else {
      bf16x8 o0, o1;
      float s = 0.f;
#pragma unroll
      for (int e = 0; e < 8; ++e) {
        o0[e] = (bf16)wv_[e];     s += wv_[e] * wv_[e];
        o1[e] = (bf16)wv_[e + 8]; s += wv_[e + 8] * wv_[e + 8];
      }
      bf16* op = Mo + (size_t)bz * S_DIM * D_DIM + (size_t)gi * D_DIM + col0 + sub * 16;
      *(bf16x8*)(op)     = o0;
      *(bf16x8*)(op + 8) = o1;
      s += __shfl_xor(s, 1);
      s += __shfl_xor(s, 2);
      if (sub == 0) atomicAdd(m2out + (size_t)bz * S_DIM + gi, s);
    }
  }
}

extern "C" void kernel_launch(void* const* d_in, const int* in_sizes, int n_in,
                              void* d_out, int out_size, void* d_ws, size_t ws_size,
                              hipStream_t stream) {
  const float* A = (const float*)d_in[0];  // (4, 2048, 2048)
  const float* V = (const float*)d_in[1];  // (4, 2048, 512)
  float* out = (float*)d_out;              // (4, 2048, 512) fp32

  char* ws = (char*)d_ws;
  bf16* Abf = (bf16*)ws;   ws += (size_t)NB * S_DIM * S_DIM * 2;       // 33.5 MB
  bf16* Vbf = (bf16*)ws;   ws += (size_t)NB * S_DIM * D_DIM * 2;       //  8.4 MB
  bf16* Vt  = (bf16*)ws;   ws += (size_t)NB * S_DIM * D_DIM * 2;       //  8.4 MB
  bf16* Mbf = (bf16*)ws;   ws += (size_t)NB * S_DIM * D_DIM * 2;       //  8.4 MB
  bf16* Wbf = (bf16*)ws;   ws += (size_t)NB * S_DIM * S_DIM * 2;       // 33.5 MB
  float* v2 = (float*)ws;  ws += (size_t)NB * S_DIM * 4;
  float* m2a = (float*)ws; ws += (size_t)NB * S_DIM * 4;
  float* m2b = (float*)ws; ws += (size_t)NB * S_DIM * 4;
  float* l1p = (float*)ws; ws += (size_t)16 * NB * S_DIM * 4;          // 512 KB

  int nA4 = NB * S_DIM * S_DIM / 4;
  cast_kernel<<<nA4 / 256, 256, 0, stream>>>(A, Abf, nA4, m2a);
  vprep_kernel<<<dim3(S_DIM / 64, NB), 256, 0, stream>>>(V, Vbf, Vt, v2);

  // M0 = A @ V  (direct: Mbf + m2a atomics; m2a zeroed by cast)
  gemmwv_kernel<0><<<dim3(D_DIM / 64, S_DIM / 128, NB), 256, 0, stream>>>(
      Abf, Vt, nullptr, Mbf, nullptr, m2a);

  // it 0: read m2a, zero m2b, W@V -> m2b
  gemmP_kernel<<<dim3(16, 16, NB), 256, 0, stream>>>(
      Mbf, Vbf, S_DIM, S_DIM, D_DIM, m2a, v2, Abf, Wbf, l1p, m2b);
  gemmwv_kernel<1><<<dim3(D_DIM / 64, S_DIM / 128, NB), 256, 0, stream>>>(
      Wbf, Vt, l1p, Mbf, nullptr, m2b);

  // it 1: read m2b, zero m2a, W@V -> m2a
  gemmP_kernel<<<dim3(16, 16, NB), 256, 0, stream>>>(
      Mbf, Vbf, S_DIM, S_DIM, D_DIM, m2b, v2, Abf, Wbf, l1p, m2a);
  gemmwv_kernel<1><<<dim3(D_DIM / 64, S_DIM / 128, NB), 256, 0, stream>>>(
      Wbf, Vt, l1p, Mbf, nullptr, m2a);

  // it 2: read m2a, final -> fp32 out
  gemmP_kernel<<<dim3(16, 16, NB), 256, 0, stream>>>(
      Mbf, Vbf, S_DIM, S_DIM, D_DIM, m2a, v2, Abf, Wbf, l1p, m2b);
  gemmwv_kernel<2><<<dim3(D_DIM / 64, S_DIM / 128, NB), 256, 0, stream>>>(
      Wbf, Vt, l1p, nullptr, out, nullptr);
}